// Round 1
// baseline (1618.097 us; speedup 1.0000x reference)
//
#include <hip/hip_runtime.h>
#include <hip/hip_bf16.h>

#define B_ 4
#define S_ 2048
#define E_ 1024
#define H_ 16
#define HD_ 64

typedef __attribute__((ext_vector_type(8))) short bf16x8;
typedef __attribute__((ext_vector_type(4))) float f32x4;

__device__ __forceinline__ float b2f(unsigned short u) {
    union { unsigned u; float f; } v; v.u = ((unsigned)u) << 16; return v.f;
}
__device__ __forceinline__ unsigned short f2b(float f) {
    union { float f; unsigned u; } v; v.f = f;
    unsigned lsb = (v.u >> 16) & 1u;
    v.u += 0x7fffu + lsb;
    return (unsigned short)(v.u >> 16);
}

// ---------------- elementwise f32 -> bf16 ----------------
__global__ void cvt_f32_to_bf16(const float* __restrict__ in,
                                unsigned short* __restrict__ out, int n8) {
    int i = blockIdx.x * blockDim.x + threadIdx.x;
    if (i >= n8) return;
    const float4* p = (const float4*)(in + (size_t)i * 8);
    float4 a = p[0], b = p[1];
    bf16x8 o;
    o[0] = (short)f2b(a.x); o[1] = (short)f2b(a.y);
    o[2] = (short)f2b(a.z); o[3] = (short)f2b(a.w);
    o[4] = (short)f2b(b.x); o[5] = (short)f2b(b.y);
    o[6] = (short)f2b(b.z); o[7] = (short)f2b(b.w);
    *(bf16x8*)(out + (size_t)i * 8) = o;
}

// ---------------- W[K][N] f32 -> Wt[N][K] bf16 ----------------
__global__ void transpose_cvt(const float* __restrict__ W,
                              unsigned short* __restrict__ Wt) {
    __shared__ float tile[32][33];
    int tx = threadIdx.x, ty = threadIdx.y;  // (32, 8)
    int x0 = blockIdx.x * 32, y0 = blockIdx.y * 32;
#pragma unroll
    for (int j = 0; j < 32; j += 8)
        tile[ty + j][tx] = W[(size_t)(y0 + ty + j) * E_ + x0 + tx];
    __syncthreads();
#pragma unroll
    for (int j = 0; j < 32; j += 8)
        Wt[(size_t)(x0 + ty + j) * E_ + y0 + tx] = f2b(tile[tx][ty + j]);
}

// ---------------- GEMM: C[M,N] = A[M,K] @ Bt[N,K]^T + bias ----------------
#define BM 128
#define BN 128
#define BK 32

__global__ __launch_bounds__(256) void gemm_bt(
        const unsigned short* __restrict__ A,
        const unsigned short* __restrict__ Bt,
        const float* __restrict__ bias,
        float* __restrict__ Cf, unsigned short* __restrict__ Cb,
        int M, int N, int K) {
    __shared__ unsigned short As[BM][BK];
    __shared__ unsigned short Bs[BN][BK];
    int t = threadIdx.x;
    int lane = t & 63, wid = t >> 6;
    int wr = wid >> 1, wc = wid & 1;
    int bx = blockIdx.x, by = blockIdx.y;
    const size_t abase = (size_t)by * BM * K;
    const size_t bbase = (size_t)bx * BN * K;

    f32x4 acc[4][4] = {};

    for (int ko = 0; ko < K; ko += BK) {
#pragma unroll
        for (int i = 0; i < 2; ++i) {
            int c = t + i * 256;           // 0..511 chunks of 8 bf16
            int row = c >> 2;              // /4 chunks per 32-wide row
            int kc = (c & 3) << 3;
            *(uint4*)&As[row][kc] =
                *(const uint4*)&A[abase + (size_t)row * K + ko + kc];
            *(uint4*)&Bs[row][kc] =
                *(const uint4*)&Bt[bbase + (size_t)row * K + ko + kc];
        }
        __syncthreads();
        int kg = (lane >> 4) << 3;  // k offset 0,8,16,24
        bf16x8 af[4], bfr[4];
#pragma unroll
        for (int i = 0; i < 4; ++i) {
            af[i]  = *(const bf16x8*)&As[wr * 64 + i * 16 + (lane & 15)][kg];
            bfr[i] = *(const bf16x8*)&Bs[wc * 64 + i * 16 + (lane & 15)][kg];
        }
#pragma unroll
        for (int i = 0; i < 4; ++i)
#pragma unroll
            for (int j = 0; j < 4; ++j)
                acc[i][j] = __builtin_amdgcn_mfma_f32_16x16x32_bf16(
                    af[i], bfr[j], acc[i][j], 0, 0, 0);
        __syncthreads();
    }

#pragma unroll
    for (int i = 0; i < 4; ++i) {
        int row0 = by * BM + wr * 64 + i * 16 + ((lane >> 4) << 2);
#pragma unroll
        for (int j = 0; j < 4; ++j) {
            int col = bx * BN + wc * 64 + j * 16 + (lane & 15);
            float bv = bias[col];
#pragma unroll
            for (int r = 0; r < 4; ++r) {
                int row = row0 + r;
                float v = acc[i][j][r] + bv;
                if (Cf) Cf[(size_t)row * N + col] = v;
                else    Cb[(size_t)row * N + col] = f2b(v);
            }
        }
    }
}

// ---------------- causal flash attention, fp32 VALU ----------------
// one thread = one query row; K/V tiles (64 rows) staged to LDS as f32
__global__ __launch_bounds__(256, 1) void attn_flash(
        const unsigned short* __restrict__ Qb,
        const unsigned short* __restrict__ Kb,
        const unsigned short* __restrict__ Vb,
        unsigned short* __restrict__ Yb) {
    __shared__ float Ks[64][64];
    __shared__ float Vs[64][64];
    int t = threadIdx.x;
    int bh = blockIdx.x;
    int b = bh >> 4, h = bh & 15;
    int qt = blockIdx.y;
    int sq = qt * 256 + t;
    size_t qoff = ((size_t)b * S_ + sq) * E_ + h * HD_;

    float q[64], y[64];
#pragma unroll
    for (int j = 0; j < 8; ++j) {
        bf16x8 v = *(const bf16x8*)&Qb[qoff + j * 8];
#pragma unroll
        for (int e = 0; e < 8; ++e)
            q[j * 8 + e] = b2f((unsigned short)v[e]) * 0.125f;  // 1/sqrt(64)
    }
#pragma unroll
    for (int d = 0; d < 64; ++d) y[d] = 0.f;
    float m = -1e30f, l = 0.f;

    int srow = t >> 2, d0 = (t & 3) * 16;
    int ntiles = qt * 4 + 4;
    for (int kt = 0; kt < ntiles; ++kt) {
        int k0 = kt * 64;
        __syncthreads();
        size_t koff = ((size_t)b * S_ + k0 + srow) * E_ + h * HD_ + d0;
#pragma unroll
        for (int u = 0; u < 2; ++u) {
            bf16x8 kv = *(const bf16x8*)&Kb[koff + u * 8];
            bf16x8 vv = *(const bf16x8*)&Vb[koff + u * 8];
#pragma unroll
            for (int e = 0; e < 8; ++e) {
                Ks[srow][d0 + u * 8 + e] = b2f((unsigned short)kv[e]);
                Vs[srow][d0 + u * 8 + e] = b2f((unsigned short)vv[e]);
            }
        }
        __syncthreads();
        int kmax = sq - k0 + 1;
        if (kmax > 64) kmax = 64;
        for (int kk = 0; kk < kmax; ++kk) {
            const float4* Kr = (const float4*)&Ks[kk][0];
            const float4* Vr = (const float4*)&Vs[kk][0];
            float px = 0.f, py = 0.f, pz = 0.f, pw = 0.f;
#pragma unroll
            for (int d = 0; d < 16; ++d) {
                float4 kv = Kr[d];
                px = fmaf(q[4 * d + 0], kv.x, px);
                py = fmaf(q[4 * d + 1], kv.y, py);
                pz = fmaf(q[4 * d + 2], kv.z, pz);
                pw = fmaf(q[4 * d + 3], kv.w, pw);
            }
            float s = (px + py) + (pz + pw);
            if (s > m) {
                float corr = __expf(m - s);
                l *= corr;
#pragma unroll
                for (int d = 0; d < 64; ++d) y[d] *= corr;
                m = s;
            }
            float p = __expf(s - m);
            l += p;
#pragma unroll
            for (int d = 0; d < 16; ++d) {
                float4 vv = Vr[d];
                y[4 * d + 0] = fmaf(p, vv.x, y[4 * d + 0]);
                y[4 * d + 1] = fmaf(p, vv.y, y[4 * d + 1]);
                y[4 * d + 2] = fmaf(p, vv.z, y[4 * d + 2]);
                y[4 * d + 3] = fmaf(p, vv.w, y[4 * d + 3]);
            }
        }
    }
    float inv = 1.f / l;
#pragma unroll
    for (int j = 0; j < 8; ++j) {
        bf16x8 o;
#pragma unroll
        for (int e = 0; e < 8; ++e) o[e] = (short)f2b(y[j * 8 + e] * inv);
        *(bf16x8*)&Yb[qoff + j * 8] = o;
    }
}

extern "C" void kernel_launch(void* const* d_in, const int* in_sizes, int n_in,
                              void* d_out, int out_size, void* d_ws, size_t ws_size,
                              hipStream_t stream) {
    const float* x  = (const float*)d_in[0];
    const float* Wq = (const float*)d_in[1];
    const float* bq = (const float*)d_in[2];
    const float* Wk = (const float*)d_in[3];
    const float* bk = (const float*)d_in[4];
    const float* Wv = (const float*)d_in[5];
    const float* bv = (const float*)d_in[6];
    const float* Wo = (const float*)d_in[7];
    const float* bo = (const float*)d_in[8];

    char* ws = (char*)d_ws;
    const size_t M = (size_t)B_ * S_;  // 8192
    unsigned short* xb  = (unsigned short*)ws;                    // 16 MB (reused as Y)
    unsigned short* Wtq = (unsigned short*)(ws + (16ull << 20));  // 2 MB each
    unsigned short* Wtk = (unsigned short*)(ws + (18ull << 20));
    unsigned short* Wtv = (unsigned short*)(ws + (20ull << 20));
    unsigned short* Wto = (unsigned short*)(ws + (22ull << 20));
    unsigned short* Qb  = (unsigned short*)(ws + (24ull << 20));  // 16 MB
    unsigned short* Kb  = (unsigned short*)(ws + (40ull << 20));  // 16 MB
    unsigned short* Vb  = (unsigned short*)(ws + (56ull << 20));  // 16 MB
    unsigned short* Yb  = xb;                                     // reuse

    int n8 = (int)(M * E_ / 8);
    cvt_f32_to_bf16<<<(n8 + 255) / 256, 256, 0, stream>>>(x, xb, n8);

    dim3 tb(32, 8), tg(32, 32);
    transpose_cvt<<<tg, tb, 0, stream>>>(Wq, Wtq);
    transpose_cvt<<<tg, tb, 0, stream>>>(Wk, Wtk);
    transpose_cvt<<<tg, tb, 0, stream>>>(Wv, Wtv);
    transpose_cvt<<<tg, tb, 0, stream>>>(Wo, Wto);

    dim3 gg(E_ / BN, M / BM);  // (8, 64)
    gemm_bt<<<gg, 256, 0, stream>>>(xb, Wtq, bq, nullptr, Qb, (int)M, E_, E_);
    gemm_bt<<<gg, 256, 0, stream>>>(xb, Wtk, bk, nullptr, Kb, (int)M, E_, E_);
    gemm_bt<<<gg, 256, 0, stream>>>(xb, Wtv, bv, nullptr, Vb, (int)M, E_, E_);

    dim3 ag(B_ * H_, S_ / 256);  // (64, 8)
    attn_flash<<<ag, 256, 0, stream>>>(Qb, Kb, Vb, Yb);

    gemm_bt<<<gg, 256, 0, stream>>>(Yb, Wto, bo, (float*)d_out, nullptr, (int)M, E_, E_);
}

// Round 2
// 287.248 us; speedup vs baseline: 5.6331x; 5.6331x over previous
//
#include <hip/hip_runtime.h>
#include <hip/hip_bf16.h>

#define B_ 4
#define S_ 2048
#define E_ 1024
#define H_ 16
#define HD_ 64

typedef __attribute__((ext_vector_type(8))) short bf16x8;
typedef __attribute__((ext_vector_type(4))) float f32x4;

__device__ __forceinline__ float b2f(unsigned short u) {
    union { unsigned u; float f; } v; v.u = ((unsigned)u) << 16; return v.f;
}
__device__ __forceinline__ unsigned short f2b(float f) {
    union { float f; unsigned u; } v; v.f = f;
    unsigned lsb = (v.u >> 16) & 1u;
    v.u += 0x7fffu + lsb;
    return (unsigned short)(v.u >> 16);
}

// ---------------- elementwise f32 -> bf16 ----------------
__global__ void cvt_f32_to_bf16(const float* __restrict__ in,
                                unsigned short* __restrict__ out, int n8) {
    int i = blockIdx.x * blockDim.x + threadIdx.x;
    if (i >= n8) return;
    const float4* p = (const float4*)(in + (size_t)i * 8);
    float4 a = p[0], b = p[1];
    bf16x8 o;
    o[0] = (short)f2b(a.x); o[1] = (short)f2b(a.y);
    o[2] = (short)f2b(a.z); o[3] = (short)f2b(a.w);
    o[4] = (short)f2b(b.x); o[5] = (short)f2b(b.y);
    o[6] = (short)f2b(b.z); o[7] = (short)f2b(b.w);
    *(bf16x8*)(out + (size_t)i * 8) = o;
}

// ---------------- W[K][N] f32 -> Wt[N][K] bf16 ----------------
__global__ void transpose_cvt(const float* __restrict__ W,
                              unsigned short* __restrict__ Wt) {
    __shared__ float tile[32][33];
    int tx = threadIdx.x, ty = threadIdx.y;  // (32, 8)
    int x0 = blockIdx.x * 32, y0 = blockIdx.y * 32;
#pragma unroll
    for (int j = 0; j < 32; j += 8)
        tile[ty + j][tx] = W[(size_t)(y0 + ty + j) * E_ + x0 + tx];
    __syncthreads();
#pragma unroll
    for (int j = 0; j < 32; j += 8)
        Wt[(size_t)(x0 + ty + j) * E_ + y0 + tx] = f2b(tile[tx][ty + j]);
}

// ---------------- GEMM: C[M,N] = A[M,K] @ Bt[N,K]^T + bias ----------------
#define BM 128
#define BN 128
#define BK 32

__global__ __launch_bounds__(256) void gemm_bt(
        const unsigned short* __restrict__ A,
        const unsigned short* __restrict__ Bt,
        const float* __restrict__ bias,
        float* __restrict__ Cf, unsigned short* __restrict__ Cb,
        int M, int N, int K) {
    __shared__ unsigned short As[BM][BK];
    __shared__ unsigned short Bs[BN][BK];
    int t = threadIdx.x;
    int lane = t & 63, wid = t >> 6;
    int wr = wid >> 1, wc = wid & 1;
    int bx = blockIdx.x, by = blockIdx.y;
    const size_t abase = (size_t)by * BM * K;
    const size_t bbase = (size_t)bx * BN * K;

    f32x4 acc[4][4] = {};

    for (int ko = 0; ko < K; ko += BK) {
#pragma unroll
        for (int i = 0; i < 2; ++i) {
            int c = t + i * 256;           // 0..511 chunks of 8 bf16
            int row = c >> 2;              // /4 chunks per 32-wide row
            int kc = (c & 3) << 3;
            *(uint4*)&As[row][kc] =
                *(const uint4*)&A[abase + (size_t)row * K + ko + kc];
            *(uint4*)&Bs[row][kc] =
                *(const uint4*)&Bt[bbase + (size_t)row * K + ko + kc];
        }
        __syncthreads();
        int kg = (lane >> 4) << 3;  // k offset 0,8,16,24
        bf16x8 af[4], bfr[4];
#pragma unroll
        for (int i = 0; i < 4; ++i) {
            af[i]  = *(const bf16x8*)&As[wr * 64 + i * 16 + (lane & 15)][kg];
            bfr[i] = *(const bf16x8*)&Bs[wc * 64 + i * 16 + (lane & 15)][kg];
        }
#pragma unroll
        for (int i = 0; i < 4; ++i)
#pragma unroll
            for (int j = 0; j < 4; ++j)
                acc[i][j] = __builtin_amdgcn_mfma_f32_16x16x32_bf16(
                    af[i], bfr[j], acc[i][j], 0, 0, 0);
        __syncthreads();
    }

#pragma unroll
    for (int i = 0; i < 4; ++i) {
        int row0 = by * BM + wr * 64 + i * 16 + ((lane >> 4) << 2);
#pragma unroll
        for (int j = 0; j < 4; ++j) {
            int col = bx * BN + wc * 64 + j * 16 + (lane & 15);
            float bv = bias[col];
#pragma unroll
            for (int r = 0; r < 4; ++r) {
                int row = row0 + r;
                float v = acc[i][j][r] + bv;
                if (Cf) Cf[(size_t)row * N + col] = v;
                else    Cb[(size_t)row * N + col] = f2b(v);
            }
        }
    }
}

// ---------------- causal flash attention, MFMA ----------------
// block = 4 waves; wave w owns 32 query rows; Q-tile = 128 rows; KV tile = 64
#define KVBLK 64

__global__ __launch_bounds__(256) void attn_mfma(
        const unsigned short* __restrict__ Qb,
        const unsigned short* __restrict__ Kb,
        const unsigned short* __restrict__ Vb,
        unsigned short* __restrict__ Yb) {
    // K row-major [key][d], V transposed [d][key]; both XOR-swizzled
    __shared__ unsigned short Ks[KVBLK][64];
    __shared__ unsigned short Vt[64][KVBLK];
    __shared__ unsigned short Pl[4][32][64];  // per-wave P[q][key], swizzled

    int t = threadIdx.x;
    int lane = t & 63, wid = t >> 6;
    int l15 = lane & 15, lg = lane >> 4;
    int bh = blockIdx.x;
    int b = bh >> 4, h = bh & 15;
    int by = gridDim.y - 1 - blockIdx.y;   // heavy blocks first
    int q0 = by * 128;
    int qbase = q0 + wid * 32;

    // ---- load Q fragments (pre-scaled by 1/sqrt(64)) ----
    bf16x8 qf[2][2];
#pragma unroll
    for (int mt = 0; mt < 2; ++mt)
#pragma unroll
        for (int ks = 0; ks < 2; ++ks) {
            int row = qbase + mt * 16 + l15;
            bf16x8 v = *(const bf16x8*)&Qb[((size_t)(b * S_ + row)) * E_ +
                                           h * 64 + ks * 32 + lg * 8];
#pragma unroll
            for (int e = 0; e < 8; ++e)
                qf[mt][ks][e] = (short)f2b(b2f((unsigned short)v[e]) * 0.125f);
        }

    f32x4 yacc[2][4] = {};
    float m_[2][4], l_[2][4];
#pragma unroll
    for (int mt = 0; mt < 2; ++mt)
#pragma unroll
        for (int r = 0; r < 4; ++r) { m_[mt][r] = -1e30f; l_[mt][r] = 0.f; }

    int ntiles = by * 2 + 2;
    for (int kt = 0; kt < ntiles; ++kt) {
        int k0 = kt * KVBLK;
        __syncthreads();
        // ---- stage K (row-major) and V (transposed), swizzled ----
        {
            int row = t >> 2;            // key 0..63
            int c4 = (t & 3) * 16;       // d base, 2 chunks of 8
            size_t g = ((size_t)(b * S_ + k0 + row)) * E_ + h * 64 + c4;
            bf16x8 k0v = *(const bf16x8*)&Kb[g];
            bf16x8 k1v = *(const bf16x8*)&Kb[g + 8];
            bf16x8 v0v = *(const bf16x8*)&Vb[g];
            bf16x8 v1v = *(const bf16x8*)&Vb[g + 8];
            int sw = (row & 7) << 3;
            *(bf16x8*)&Ks[row][c4 ^ sw] = k0v;
            *(bf16x8*)&Ks[row][(c4 + 8) ^ sw] = k1v;
#pragma unroll
            for (int e = 0; e < 8; ++e) {
                int d0 = c4 + e, d1 = c4 + 8 + e;
                Vt[d0][row ^ ((d0 & 7) << 3)] = (unsigned short)v0v[e];
                Vt[d1][row ^ ((d1 & 7) << 3)] = (unsigned short)v1v[e];
            }
        }
        __syncthreads();

        if (k0 <= qbase + 31) {          // not fully masked for this wave
            bool boundary = (k0 + KVBLK - 1 > qbase);
            // ---- S = Q K^T ----
            f32x4 sacc[2][4] = {};
#pragma unroll
            for (int ks = 0; ks < 2; ++ks) {
                bf16x8 kf[4];
#pragma unroll
                for (int n = 0; n < 4; ++n)
                    kf[n] = *(const bf16x8*)&Ks[n * 16 + l15]
                              [(ks * 32 + lg * 8) ^ ((l15 & 7) << 3)];
#pragma unroll
                for (int mt = 0; mt < 2; ++mt)
#pragma unroll
                    for (int n = 0; n < 4; ++n)
                        sacc[mt][n] = __builtin_amdgcn_mfma_f32_16x16x32_bf16(
                            qf[mt][ks], kf[n], sacc[mt][n], 0, 0, 0);
            }
            // ---- causal mask ----
            if (boundary) {
#pragma unroll
                for (int mt = 0; mt < 2; ++mt)
#pragma unroll
                    for (int n = 0; n < 4; ++n) {
                        int ka = k0 + n * 16 + l15;
#pragma unroll
                        for (int r = 0; r < 4; ++r) {
                            int qa = qbase + mt * 16 + lg * 4 + r;
                            if (ka > qa) sacc[mt][n][r] = -3e38f;
                        }
                    }
            }
            // ---- online softmax ----
#pragma unroll
            for (int mt = 0; mt < 2; ++mt)
#pragma unroll
                for (int r = 0; r < 4; ++r) {
                    float pm = fmaxf(fmaxf(sacc[mt][0][r], sacc[mt][1][r]),
                                     fmaxf(sacc[mt][2][r], sacc[mt][3][r]));
#pragma unroll
                    for (int d = 1; d < 16; d <<= 1)
                        pm = fmaxf(pm, __shfl_xor(pm, d));
                    float mn = fmaxf(m_[mt][r], pm);
                    float corr = __expf(m_[mt][r] - mn);
                    m_[mt][r] = mn;
                    float rs = 0.f;
#pragma unroll
                    for (int n = 0; n < 4; ++n) {
                        float p = __expf(sacc[mt][n][r] - mn);
                        sacc[mt][n][r] = p;
                        rs += p;
                        yacc[mt][n][r] *= corr;
                    }
#pragma unroll
                    for (int d = 1; d < 16; d <<= 1)
                        rs += __shfl_xor(rs, d);
                    l_[mt][r] = l_[mt][r] * corr + rs;
                }
            // ---- write P (bf16, swizzled) ----
#pragma unroll
            for (int mt = 0; mt < 2; ++mt)
#pragma unroll
                for (int n = 0; n < 4; ++n)
#pragma unroll
                    for (int r = 0; r < 4; ++r) {
                        int q = mt * 16 + lg * 4 + r;
                        Pl[wid][q][(n * 16 + l15) ^ ((q & 7) << 3)] =
                            f2b(sacc[mt][n][r]);
                    }
            asm volatile("s_waitcnt lgkmcnt(0)" ::: "memory");
            // ---- Y += P V ----
#pragma unroll
            for (int ks = 0; ks < 2; ++ks) {
                bf16x8 pa[2], vf[4];
#pragma unroll
                for (int mt = 0; mt < 2; ++mt)
                    pa[mt] = *(const bf16x8*)&Pl[wid][mt * 16 + l15]
                               [(ks * 32 + lg * 8) ^ ((l15 & 7) << 3)];
#pragma unroll
                for (int n = 0; n < 4; ++n)
                    vf[n] = *(const bf16x8*)&Vt[n * 16 + l15]
                              [(ks * 32 + lg * 8) ^ ((l15 & 7) << 3)];
#pragma unroll
                for (int mt = 0; mt < 2; ++mt)
#pragma unroll
                    for (int n = 0; n < 4; ++n)
                        yacc[mt][n] = __builtin_amdgcn_mfma_f32_16x16x32_bf16(
                            pa[mt], vf[n], yacc[mt][n], 0, 0, 0);
            }
        }
    }

    // ---- epilogue: Y / l ----
#pragma unroll
    for (int mt = 0; mt < 2; ++mt)
#pragma unroll
        for (int n = 0; n < 4; ++n)
#pragma unroll
            for (int r = 0; r < 4; ++r) {
                int row = qbase + mt * 16 + lg * 4 + r;
                int d = n * 16 + l15;
                float v = yacc[mt][n][r] / l_[mt][r];
                Yb[((size_t)(b * S_ + row)) * E_ + h * 64 + d] = f2b(v);
            }
}

extern "C" void kernel_launch(void* const* d_in, const int* in_sizes, int n_in,
                              void* d_out, int out_size, void* d_ws, size_t ws_size,
                              hipStream_t stream) {
    const float* x  = (const float*)d_in[0];
    const float* Wq = (const float*)d_in[1];
    const float* bq = (const float*)d_in[2];
    const float* Wk = (const float*)d_in[3];
    const float* bk = (const float*)d_in[4];
    const float* Wv = (const float*)d_in[5];
    const float* bv = (const float*)d_in[6];
    const float* Wo = (const float*)d_in[7];
    const float* bo = (const float*)d_in[8];

    char* ws = (char*)d_ws;
    const size_t M = (size_t)B_ * S_;  // 8192
    unsigned short* xb  = (unsigned short*)ws;                    // 16 MB (reused as Y)
    unsigned short* Wtq = (unsigned short*)(ws + (16ull << 20));  // 2 MB each
    unsigned short* Wtk = (unsigned short*)(ws + (18ull << 20));
    unsigned short* Wtv = (unsigned short*)(ws + (20ull << 20));
    unsigned short* Wto = (unsigned short*)(ws + (22ull << 20));
    unsigned short* Qb  = (unsigned short*)(ws + (24ull << 20));  // 16 MB
    unsigned short* Kb  = (unsigned short*)(ws + (40ull << 20));  // 16 MB
    unsigned short* Vb  = (unsigned short*)(ws + (56ull << 20));  // 16 MB
    unsigned short* Yb  = xb;                                     // reuse

    int n8 = (int)(M * E_ / 8);
    cvt_f32_to_bf16<<<(n8 + 255) / 256, 256, 0, stream>>>(x, xb, n8);

    dim3 tb(32, 8), tg(32, 32);
    transpose_cvt<<<tg, tb, 0, stream>>>(Wq, Wtq);
    transpose_cvt<<<tg, tb, 0, stream>>>(Wk, Wtk);
    transpose_cvt<<<tg, tb, 0, stream>>>(Wv, Wtv);
    transpose_cvt<<<tg, tb, 0, stream>>>(Wo, Wto);

    dim3 gg(E_ / BN, M / BM);  // (8, 64)
    gemm_bt<<<gg, 256, 0, stream>>>(xb, Wtq, bq, nullptr, Qb, (int)M, E_, E_);
    gemm_bt<<<gg, 256, 0, stream>>>(xb, Wtk, bk, nullptr, Kb, (int)M, E_, E_);
    gemm_bt<<<gg, 256, 0, stream>>>(xb, Wtv, bv, nullptr, Vb, (int)M, E_, E_);

    dim3 ag(B_ * H_, S_ / 128);  // (64, 16)
    attn_mfma<<<ag, 256, 0, stream>>>(Qb, Kb, Vb, Yb);

    gemm_bt<<<gg, 256, 0, stream>>>(Yb, Wto, bo, (float*)d_out, nullptr, (int)M, E_, E_);
}

// Round 4
// 256.722 us; speedup vs baseline: 6.3029x; 1.1189x over previous
//
#include <hip/hip_runtime.h>
#include <hip/hip_bf16.h>

#define B_ 4
#define S_ 2048
#define E_ 1024
#define H_ 16
#define HD_ 64

typedef __attribute__((ext_vector_type(8))) short bf16x8;
typedef __attribute__((ext_vector_type(4))) float f32x4;

__device__ __forceinline__ float b2f(unsigned short u) {
    union { unsigned u; float f; } v; v.u = ((unsigned)u) << 16; return v.f;
}
__device__ __forceinline__ unsigned short f2b(float f) {
    union { float f; unsigned u; } v; v.f = f;
    unsigned lsb = (v.u >> 16) & 1u;
    v.u += 0x7fffu + lsb;
    return (unsigned short)(v.u >> 16);
}
__device__ __forceinline__ unsigned cvtpk_bf16(float lo, float hi) {
    unsigned r;
    asm("v_cvt_pk_bf16_f32 %0, %1, %2" : "=v"(r) : "v"(lo), "v"(hi));
    return r;
}

// ---------------- elementwise f32 -> bf16 ----------------
__global__ void cvt_f32_to_bf16(const float* __restrict__ in,
                                unsigned short* __restrict__ out, int n8) {
    int i = blockIdx.x * blockDim.x + threadIdx.x;
    if (i >= n8) return;
    const float4* p = (const float4*)(in + (size_t)i * 8);
    float4 a = p[0], b = p[1];
    bf16x8 o;
    o[0] = (short)f2b(a.x); o[1] = (short)f2b(a.y);
    o[2] = (short)f2b(a.z); o[3] = (short)f2b(a.w);
    o[4] = (short)f2b(b.x); o[5] = (short)f2b(b.y);
    o[6] = (short)f2b(b.z); o[7] = (short)f2b(b.w);
    *(bf16x8*)(out + (size_t)i * 8) = o;
}

// ---------------- W[K][N] f32 -> Wt[N][K] bf16 ----------------
__global__ void transpose_cvt(const float* __restrict__ W,
                              unsigned short* __restrict__ Wt) {
    __shared__ float tile[32][33];
    int tx = threadIdx.x, ty = threadIdx.y;  // (32, 8)
    int x0 = blockIdx.x * 32, y0 = blockIdx.y * 32;
#pragma unroll
    for (int j = 0; j < 32; j += 8)
        tile[ty + j][tx] = W[(size_t)(y0 + ty + j) * E_ + x0 + tx];
    __syncthreads();
#pragma unroll
    for (int j = 0; j < 32; j += 8)
        Wt[(size_t)(x0 + ty + j) * E_ + y0 + tx] = f2b(tile[tx][ty + j]);
}

// ---------------- GEMM: C[M,N] = A[M,K] @ Bt[N,K]^T + bias ----------------
#define BM 128
#define BN 128
#define BK 32

__global__ __launch_bounds__(256) void gemm_bt(
        const unsigned short* __restrict__ A,
        const unsigned short* __restrict__ Bt,
        const float* __restrict__ bias,
        float* __restrict__ Cf, unsigned short* __restrict__ Cb,
        int M, int N, int K) {
    __shared__ unsigned short As[BM][BK];
    __shared__ unsigned short Bs[BN][BK];
    int t = threadIdx.x;
    int lane = t & 63, wid = t >> 6;
    int wr = wid >> 1, wc = wid & 1;
    int bx = blockIdx.x, by = blockIdx.y;
    const size_t abase = (size_t)by * BM * K;
    const size_t bbase = (size_t)bx * BN * K;

    f32x4 acc[4][4] = {};

    for (int ko = 0; ko < K; ko += BK) {
#pragma unroll
        for (int i = 0; i < 2; ++i) {
            int c = t + i * 256;           // 0..511 chunks of 8 bf16
            int row = c >> 2;              // /4 chunks per 32-wide row
            int kc = (c & 3) << 3;
            *(uint4*)&As[row][kc] =
                *(const uint4*)&A[abase + (size_t)row * K + ko + kc];
            *(uint4*)&Bs[row][kc] =
                *(const uint4*)&Bt[bbase + (size_t)row * K + ko + kc];
        }
        __syncthreads();
        int kg = (lane >> 4) << 3;  // k offset 0,8,16,24
        bf16x8 af[4], bfr[4];
#pragma unroll
        for (int i = 0; i < 4; ++i) {
            af[i]  = *(const bf16x8*)&As[wr * 64 + i * 16 + (lane & 15)][kg];
            bfr[i] = *(const bf16x8*)&Bs[wc * 64 + i * 16 + (lane & 15)][kg];
        }
#pragma unroll
        for (int i = 0; i < 4; ++i)
#pragma unroll
            for (int j = 0; j < 4; ++j)
                acc[i][j] = __builtin_amdgcn_mfma_f32_16x16x32_bf16(
                    af[i], bfr[j], acc[i][j], 0, 0, 0);
        __syncthreads();
    }

#pragma unroll
    for (int i = 0; i < 4; ++i) {
        int row0 = by * BM + wr * 64 + i * 16 + ((lane >> 4) << 2);
#pragma unroll
        for (int j = 0; j < 4; ++j) {
            int col = bx * BN + wc * 64 + j * 16 + (lane & 15);
            float bv = bias[col];
#pragma unroll
            for (int r = 0; r < 4; ++r) {
                int row = row0 + r;
                float v = acc[i][j][r] + bv;
                if (Cf) Cf[(size_t)row * N + col] = v;
                else    Cb[(size_t)row * N + col] = f2b(v);
            }
        }
    }
}

// ---------------- causal flash attention, swapped-QK^T MFMA ----------------
// block = 4 waves; wave owns 32 q rows; KV tile = 64.
// S^T = mfma(K, Q): lane holds col q = lane&15, rows key = n*16+lg*4+r.
// Softmax in-register (2 shfl per reduce). P packed (cvt_pk) -> per-wave
// swizzled LDS -> PV via proven 16x16x32 MFMA.
#define KVBLK 64

__global__ __launch_bounds__(256) void attn_mfma(
        const unsigned short* __restrict__ Qb,
        const unsigned short* __restrict__ Kb,
        const unsigned short* __restrict__ Vb,
        unsigned short* __restrict__ Yb) {
    __shared__ unsigned short Ks[KVBLK][64];  // [key][d], col ^= (key&7)<<3
    __shared__ unsigned short Vt[64][KVBLK];  // [d][key], col ^= sig(d)<<3
    __shared__ unsigned short Pl[4][32][64];  // per-wave P[q][key], col ^= (q&7)<<3

    int t = threadIdx.x;
    int lane = t & 63, wid = t >> 6;
    int l15 = lane & 15, lg = lane >> 4;
    int bh = blockIdx.x;
    int b = bh >> 4, h = bh & 15;
    int by = gridDim.y - 1 - blockIdx.y;   // heavy blocks first
    int qbase = by * 128 + wid * 32;
    int vidx = lg << 4;                    // bpermute byte base: lane lg*4+r

    // ---- Q fragments, scale = 1/sqrt(64) * log2(e) (exp2 domain) ----
    const float qscale = 0.125f * 1.44269504f;
    bf16x8 qf[2][2];
#pragma unroll
    for (int mt = 0; mt < 2; ++mt)
#pragma unroll
        for (int ks = 0; ks < 2; ++ks) {
            int row = qbase + mt * 16 + l15;
            bf16x8 v = *(const bf16x8*)&Qb[((size_t)(b * S_ + row)) * E_ +
                                           h * 64 + ks * 32 + lg * 8];
#pragma unroll
            for (int e = 0; e < 8; ++e)
                qf[mt][ks][e] = (short)f2b(b2f((unsigned short)v[e]) * qscale);
        }

    f32x4 yacc[2][4] = {};
    float m_[2] = {-1e30f, -1e30f}, l_[2] = {0.f, 0.f};

    int ntiles = by * 2 + 2;
    for (int kt = 0; kt < ntiles; ++kt) {
        int k0 = kt * KVBLK;
        __syncthreads();
        // ---- stage K (row-major) and V (transposed) ----
        {
            int key = t >> 2;            // 0..63
            int c4 = (t & 3) * 16;       // d base, 2 chunks of 8
            size_t g = ((size_t)(b * S_ + k0 + key)) * E_ + h * 64 + c4;
            bf16x8 k0v = *(const bf16x8*)&Kb[g];
            bf16x8 k1v = *(const bf16x8*)&Kb[g + 8];
            bf16x8 v0v = *(const bf16x8*)&Vb[g];
            bf16x8 v1v = *(const bf16x8*)&Vb[g + 8];
            int swk = (key & 7) << 3;
            *(bf16x8*)&Ks[key][c4 ^ swk] = k0v;
            *(bf16x8*)&Ks[key][(c4 + 8) ^ swk] = k1v;
#pragma unroll
            for (int e = 0; e < 8; ++e) {
                int d0 = c4 + e, d1 = c4 + 8 + e;
                int s0 = (d0 & 7) ^ ((d0 >> 3) & 7);
                int s1 = (d1 & 7) ^ ((d1 >> 3) & 7);
                Vt[d0][key ^ (s0 << 3)] = (unsigned short)v0v[e];
                Vt[d1][key ^ (s1 << 3)] = (unsigned short)v1v[e];
            }
        }
        __syncthreads();

        if (k0 <= qbase + 31) {          // wave not fully masked
            bool boundary = (k0 + KVBLK - 1 > qbase);
            // ---- S^T = K Q^T : rows key (A side), cols q (B side) ----
            f32x4 sacc[2][4] = {};
#pragma unroll
            for (int ks = 0; ks < 2; ++ks) {
                bf16x8 kf[4];
#pragma unroll
                for (int n = 0; n < 4; ++n)
                    kf[n] = *(const bf16x8*)&Ks[n * 16 + l15]
                              [(ks * 32 + lg * 8) ^ ((l15 & 7) << 3)];
#pragma unroll
                for (int mt = 0; mt < 2; ++mt)
#pragma unroll
                    for (int n = 0; n < 4; ++n)
                        sacc[mt][n] = __builtin_amdgcn_mfma_f32_16x16x32_bf16(
                            kf[n], qf[mt][ks], sacc[mt][n], 0, 0, 0);
            }

#pragma unroll
            for (int mt = 0; mt < 2; ++mt) {
                int qv = qbase + mt * 16 + l15;   // this lane's q row
                if (boundary) {
#pragma unroll
                    for (int n = 0; n < 4; ++n)
#pragma unroll
                        for (int r = 0; r < 4; ++r)
                            if (k0 + n * 16 + lg * 4 + r > qv)
                                sacc[mt][n][r] = -3e38f;
                }
                // ---- online softmax over keys (in-reg + 2 shfl) ----
                float pm = -3e38f;
#pragma unroll
                for (int n = 0; n < 4; ++n)
#pragma unroll
                    for (int r = 0; r < 4; ++r)
                        pm = fmaxf(pm, sacc[mt][n][r]);
                pm = fmaxf(pm, __shfl_xor(pm, 16));
                pm = fmaxf(pm, __shfl_xor(pm, 32));
                float mn = fmaxf(m_[mt], pm);
                float corr = __builtin_exp2f(m_[mt] - mn);
                m_[mt] = mn;
                float rs = 0.f;
#pragma unroll
                for (int n = 0; n < 4; ++n)
#pragma unroll
                    for (int r = 0; r < 4; ++r) {
                        float p = __builtin_exp2f(sacc[mt][n][r] - mn);
                        sacc[mt][n][r] = p;
                        rs += p;
                    }
                rs += __shfl_xor(rs, 16);
                rs += __shfl_xor(rs, 32);
                l_[mt] = l_[mt] * corr + rs;
                // ---- rescale yacc rows (corr lives at lane l15=q) ----
                int ci = __float_as_int(corr);
#pragma unroll
                for (int r = 0; r < 4; ++r) {
                    float cq = __int_as_float(
                        __builtin_amdgcn_ds_bpermute(vidx + 4 * r, ci));
#pragma unroll
                    for (int n = 0; n < 4; ++n) yacc[mt][n][r] *= cq;
                }
                // ---- pack P pairs -> per-wave LDS (row q=l15) ----
#pragma unroll
                for (int n = 0; n < 4; ++n)
#pragma unroll
                    for (int j = 0; j < 2; ++j) {
                        unsigned u = cvtpk_bf16(sacc[mt][n][2 * j],
                                                sacc[mt][n][2 * j + 1]);
                        int col = (n * 16 + lg * 4 + 2 * j) ^ ((l15 & 7) << 3);
                        *(unsigned*)&Pl[wid][mt * 16 + l15][col] = u;
                    }
            }
            // ---- Y += P V  (16x16x32, A = P from LDS, B = Vt) ----
#pragma unroll
            for (int ks = 0; ks < 2; ++ks) {
                bf16x8 pa[2], vf[4];
#pragma unroll
                for (int mt = 0; mt < 2; ++mt)
                    pa[mt] = *(const bf16x8*)&Pl[wid][mt * 16 + l15]
                               [(ks * 32 + lg * 8) ^ ((l15 & 7) << 3)];
#pragma unroll
                for (int nd = 0; nd < 4; ++nd) {
                    int d = nd * 16 + l15;
                    int sig = (d & 7) ^ ((d >> 3) & 7);
                    vf[nd] = *(const bf16x8*)&Vt[d]
                               [(ks * 32 + lg * 8) ^ (sig << 3)];
                }
#pragma unroll
                for (int mt = 0; mt < 2; ++mt)
#pragma unroll
                    for (int nd = 0; nd < 4; ++nd)
                        yacc[mt][nd] = __builtin_amdgcn_mfma_f32_16x16x32_bf16(
                            pa[mt], vf[nd], yacc[mt][nd], 0, 0, 0);
            }
        }
    }

    // ---- epilogue: Y / l  (l lives at lane l15=q; rows need lg*4+r) ----
#pragma unroll
    for (int mt = 0; mt < 2; ++mt) {
        float inv = 1.f / l_[mt];
        int ii = __float_as_int(inv);
        float iv[4];
#pragma unroll
        for (int r = 0; r < 4; ++r)
            iv[r] = __int_as_float(
                __builtin_amdgcn_ds_bpermute(vidx + 4 * r, ii));
#pragma unroll
        for (int n = 0; n < 4; ++n)
#pragma unroll
            for (int r = 0; r < 4; ++r) {
                int row = qbase + mt * 16 + lg * 4 + r;
                int d = n * 16 + l15;
                Yb[((size_t)(b * S_ + row)) * E_ + h * 64 + d] =
                    f2b(yacc[mt][n][r] * iv[r]);
            }
    }
}

extern "C" void kernel_launch(void* const* d_in, const int* in_sizes, int n_in,
                              void* d_out, int out_size, void* d_ws, size_t ws_size,
                              hipStream_t stream) {
    const float* x  = (const float*)d_in[0];
    const float* Wq = (const float*)d_in[1];
    const float* bq = (const float*)d_in[2];
    const float* Wk = (const float*)d_in[3];
    const float* bk = (const float*)d_in[4];
    const float* Wv = (const float*)d_in[5];
    const float* bv = (const float*)d_in[6];
    const float* Wo = (const float*)d_in[7];
    const float* bo = (const float*)d_in[8];

    char* ws = (char*)d_ws;
    const size_t M = (size_t)B_ * S_;  // 8192
    unsigned short* xb  = (unsigned short*)ws;                    // 16 MB (reused as Y)
    unsigned short* Wtq = (unsigned short*)(ws + (16ull << 20));  // 2 MB each
    unsigned short* Wtk = (unsigned short*)(ws + (18ull << 20));
    unsigned short* Wtv = (unsigned short*)(ws + (20ull << 20));
    unsigned short* Wto = (unsigned short*)(ws + (22ull << 20));
    unsigned short* Qb  = (unsigned short*)(ws + (24ull << 20));  // 16 MB
    unsigned short* Kb  = (unsigned short*)(ws + (40ull << 20));  // 16 MB
    unsigned short* Vb  = (unsigned short*)(ws + (56ull << 20));  // 16 MB
    unsigned short* Yb  = xb;                                     // reuse

    int n8 = (int)(M * E_ / 8);
    cvt_f32_to_bf16<<<(n8 + 255) / 256, 256, 0, stream>>>(x, xb, n8);

    dim3 tb(32, 8), tg(32, 32);
    transpose_cvt<<<tg, tb, 0, stream>>>(Wq, Wtq);
    transpose_cvt<<<tg, tb, 0, stream>>>(Wk, Wtk);
    transpose_cvt<<<tg, tb, 0, stream>>>(Wv, Wtv);
    transpose_cvt<<<tg, tb, 0, stream>>>(Wo, Wto);

    dim3 gg(E_ / BN, M / BM);  // (8, 64)
    gemm_bt<<<gg, 256, 0, stream>>>(xb, Wtq, bq, nullptr, Qb, (int)M, E_, E_);
    gemm_bt<<<gg, 256, 0, stream>>>(xb, Wtk, bk, nullptr, Kb, (int)M, E_, E_);
    gemm_bt<<<gg, 256, 0, stream>>>(xb, Wtv, bv, nullptr, Vb, (int)M, E_, E_);

    dim3 ag(B_ * H_, S_ / 128);  // (64, 16)
    attn_mfma<<<ag, 256, 0, stream>>>(Qb, Kb, Vb, Yb);

    gemm_bt<<<gg, 256, 0, stream>>>(Yb, Wto, bo, (float*)d_out, nullptr, (int)M, E_, E_);
}

// Round 5
// 253.951 us; speedup vs baseline: 6.3717x; 1.0109x over previous
//
#include <hip/hip_runtime.h>
#include <hip/hip_bf16.h>

#define B_ 4
#define S_ 2048
#define E_ 1024
#define H_ 16
#define HD_ 64

typedef __attribute__((ext_vector_type(8))) short bf16x8;
typedef __attribute__((ext_vector_type(4))) float f32x4;

__device__ __forceinline__ float b2f(unsigned short u) {
    union { unsigned u; float f; } v; v.u = ((unsigned)u) << 16; return v.f;
}
__device__ __forceinline__ unsigned short f2b(float f) {
    union { float f; unsigned u; } v; v.f = f;
    unsigned lsb = (v.u >> 16) & 1u;
    v.u += 0x7fffu + lsb;
    return (unsigned short)(v.u >> 16);
}
__device__ __forceinline__ unsigned cvtpk_bf16(float lo, float hi) {
    unsigned r;
    asm("v_cvt_pk_bf16_f32 %0, %1, %2" : "=v"(r) : "v"(lo), "v"(hi));
    return r;
}

// direct global -> LDS async copy, 16B per lane (linear dest = base + lane*16)
typedef const __attribute__((address_space(1))) unsigned glb_u32;
typedef __attribute__((address_space(3))) unsigned lds_u32;
__device__ __forceinline__ void gl_lds16(const unsigned short* g,
                                         unsigned short* l) {
    __builtin_amdgcn_global_load_lds((glb_u32*)g, (lds_u32*)l, 16, 0, 0);
}

// ---------------- elementwise f32 -> bf16 ----------------
__global__ void cvt_f32_to_bf16(const float* __restrict__ in,
                                unsigned short* __restrict__ out, int n8) {
    int i = blockIdx.x * blockDim.x + threadIdx.x;
    if (i >= n8) return;
    const float4* p = (const float4*)(in + (size_t)i * 8);
    float4 a = p[0], b = p[1];
    bf16x8 o;
    o[0] = (short)f2b(a.x); o[1] = (short)f2b(a.y);
    o[2] = (short)f2b(a.z); o[3] = (short)f2b(a.w);
    o[4] = (short)f2b(b.x); o[5] = (short)f2b(b.y);
    o[6] = (short)f2b(b.z); o[7] = (short)f2b(b.w);
    *(bf16x8*)(out + (size_t)i * 8) = o;
}

// ---------------- W[K][N] f32 -> Wt[N][K] bf16 ----------------
__global__ void transpose_cvt(const float* __restrict__ W,
                              unsigned short* __restrict__ Wt) {
    __shared__ float tile[32][33];
    int tx = threadIdx.x, ty = threadIdx.y;  // (32, 8)
    int x0 = blockIdx.x * 32, y0 = blockIdx.y * 32;
#pragma unroll
    for (int j = 0; j < 32; j += 8)
        tile[ty + j][tx] = W[(size_t)(y0 + ty + j) * E_ + x0 + tx];
    __syncthreads();
#pragma unroll
    for (int j = 0; j < 32; j += 8)
        Wt[(size_t)(x0 + ty + j) * E_ + y0 + tx] = f2b(tile[tx][ty + j]);
}

// ---------------- GEMM: C[M,N] = A[M,K] @ Bt[N,K]^T + bias ----------------
#define BM 128
#define BN 128
#define BK 32

__global__ __launch_bounds__(256) void gemm_bt(
        const unsigned short* __restrict__ A,
        const unsigned short* __restrict__ Bt,
        const float* __restrict__ bias,
        float* __restrict__ Cf, unsigned short* __restrict__ Cb,
        int M, int N, int K) {
    __shared__ unsigned short As[BM][BK];
    __shared__ unsigned short Bs[BN][BK];
    int t = threadIdx.x;
    int lane = t & 63, wid = t >> 6;
    int wr = wid >> 1, wc = wid & 1;
    int bx = blockIdx.x, by = blockIdx.y;
    // per-thread source: row = t>>2 (+64 for 2nd issue), kc = (t&3)*8
    // dest LDS byte offset = t*16 (+4096) -- linear in lane, gload_lds-legal
    const int row = t >> 2, kc = (t & 3) << 3;
    const unsigned short* ga0 = A + (size_t)(by * BM + row) * K + kc;
    const unsigned short* gb0 = Bt + (size_t)(bx * BN + row) * K + kc;
    unsigned short* la0 = &As[0][0] + (size_t)t * 8;
    unsigned short* lb0 = &Bs[0][0] + (size_t)t * 8;
    const size_t step64 = (size_t)64 * K;

    f32x4 acc[4][4] = {};

    for (int ko = 0; ko < K; ko += BK) {
        gl_lds16(ga0 + ko, la0);
        gl_lds16(ga0 + ko + step64, la0 + 2048);
        gl_lds16(gb0 + ko, lb0);
        gl_lds16(gb0 + ko + step64, lb0 + 2048);
        __syncthreads();   // drains vmcnt(0) -> tiles resident
        int kg = (lane >> 4) << 3;  // k offset 0,8,16,24
        bf16x8 af[4], bfr[4];
#pragma unroll
        for (int i = 0; i < 4; ++i) {
            af[i]  = *(const bf16x8*)&As[wr * 64 + i * 16 + (lane & 15)][kg];
            bfr[i] = *(const bf16x8*)&Bs[wc * 64 + i * 16 + (lane & 15)][kg];
        }
#pragma unroll
        for (int i = 0; i < 4; ++i)
#pragma unroll
            for (int j = 0; j < 4; ++j)
                acc[i][j] = __builtin_amdgcn_mfma_f32_16x16x32_bf16(
                    af[i], bfr[j], acc[i][j], 0, 0, 0);
        __syncthreads();
    }

#pragma unroll
    for (int i = 0; i < 4; ++i) {
        int row0 = by * BM + wr * 64 + i * 16 + ((lane >> 4) << 2);
#pragma unroll
        for (int j = 0; j < 4; ++j) {
            int col = bx * BN + wc * 64 + j * 16 + (lane & 15);
            float bv = bias[col];
#pragma unroll
            for (int r = 0; r < 4; ++r) {
                int rr = row0 + r;
                float v = acc[i][j][r] + bv;
                if (Cf) Cf[(size_t)rr * N + col] = v;
                else    Cb[(size_t)rr * N + col] = f2b(v);
            }
        }
    }
}

// ---------------- causal flash attention, swapped-QK^T MFMA ----------------
// block = 4 waves; wave owns 32 q rows; KV tile = 64.
// S^T = mfma(K, Q): lane holds col q = lane&15, rows key = n*16+lg*4+r.
// Softmax in-register (2 shfl per reduce). P packed (cvt_pk) -> per-wave
// swizzled LDS -> PV via proven 16x16x32 MFMA.
#define KVBLK 64

__global__ __launch_bounds__(256) void attn_mfma(
        const unsigned short* __restrict__ Qb,
        const unsigned short* __restrict__ Kb,
        const unsigned short* __restrict__ Vb,
        unsigned short* __restrict__ Yb) {
    __shared__ unsigned short Ks[KVBLK][64];  // [key][d], col ^= (key&7)<<3
    __shared__ unsigned short Vt[64][KVBLK];  // [d][key], col ^= sig(d)<<3
    __shared__ unsigned short Pl[4][32][64];  // per-wave P[q][key], col ^= (q&7)<<3

    int t = threadIdx.x;
    int lane = t & 63, wid = t >> 6;
    int l15 = lane & 15, lg = lane >> 4;
    int bh = blockIdx.x;
    int b = bh >> 4, h = bh & 15;
    int by = gridDim.y - 1 - blockIdx.y;   // heavy blocks first
    int qbase = by * 128 + wid * 32;
    int vidx = lg << 4;                    // bpermute byte base: lane lg*4+r

    // ---- Q fragments, scale = 1/sqrt(64) * log2(e) (exp2 domain) ----
    const float qscale = 0.125f * 1.44269504f;
    bf16x8 qf[2][2];
#pragma unroll
    for (int mt = 0; mt < 2; ++mt)
#pragma unroll
        for (int ks = 0; ks < 2; ++ks) {
            int row = qbase + mt * 16 + l15;
            bf16x8 v = *(const bf16x8*)&Qb[((size_t)(b * S_ + row)) * E_ +
                                           h * 64 + ks * 32 + lg * 8];
#pragma unroll
            for (int e = 0; e < 8; ++e)
                qf[mt][ks][e] = (short)f2b(b2f((unsigned short)v[e]) * qscale);
        }

    f32x4 yacc[2][4] = {};
    float m_[2] = {-1e30f, -1e30f}, l_[2] = {0.f, 0.f};

    int ntiles = by * 2 + 2;
    for (int kt = 0; kt < ntiles; ++kt) {
        int k0 = kt * KVBLK;
        __syncthreads();
        // ---- stage K (row-major) and V (transposed) ----
        {
            int key = t >> 2;            // 0..63
            int c4 = (t & 3) * 16;       // d base, 2 chunks of 8
            size_t g = ((size_t)(b * S_ + k0 + key)) * E_ + h * 64 + c4;
            bf16x8 k0v = *(const bf16x8*)&Kb[g];
            bf16x8 k1v = *(const bf16x8*)&Kb[g + 8];
            bf16x8 v0v = *(const bf16x8*)&Vb[g];
            bf16x8 v1v = *(const bf16x8*)&Vb[g + 8];
            int swk = (key & 7) << 3;
            *(bf16x8*)&Ks[key][c4 ^ swk] = k0v;
            *(bf16x8*)&Ks[key][(c4 + 8) ^ swk] = k1v;
#pragma unroll
            for (int e = 0; e < 8; ++e) {
                int d0 = c4 + e, d1 = c4 + 8 + e;
                int s0 = (d0 & 7) ^ ((d0 >> 3) & 7);
                int s1 = (d1 & 7) ^ ((d1 >> 3) & 7);
                Vt[d0][key ^ (s0 << 3)] = (unsigned short)v0v[e];
                Vt[d1][key ^ (s1 << 3)] = (unsigned short)v1v[e];
            }
        }
        __syncthreads();

        if (k0 <= qbase + 31) {          // wave not fully masked
            bool boundary = (k0 + KVBLK - 1 > qbase);
            // ---- S^T = K Q^T : rows key (A side), cols q (B side) ----
            f32x4 sacc[2][4] = {};
#pragma unroll
            for (int ks = 0; ks < 2; ++ks) {
                bf16x8 kf[4];
#pragma unroll
                for (int n = 0; n < 4; ++n)
                    kf[n] = *(const bf16x8*)&Ks[n * 16 + l15]
                              [(ks * 32 + lg * 8) ^ ((l15 & 7) << 3)];
#pragma unroll
                for (int mt = 0; mt < 2; ++mt)
#pragma unroll
                    for (int n = 0; n < 4; ++n)
                        sacc[mt][n] = __builtin_amdgcn_mfma_f32_16x16x32_bf16(
                            kf[n], qf[mt][ks], sacc[mt][n], 0, 0, 0);
            }

#pragma unroll
            for (int mt = 0; mt < 2; ++mt) {
                int qv = qbase + mt * 16 + l15;   // this lane's q row
                if (boundary) {
#pragma unroll
                    for (int n = 0; n < 4; ++n)
#pragma unroll
                        for (int r = 0; r < 4; ++r)
                            if (k0 + n * 16 + lg * 4 + r > qv)
                                sacc[mt][n][r] = -3e38f;
                }
                // ---- online softmax over keys (in-reg + 2 shfl) ----
                float pm = -3e38f;
#pragma unroll
                for (int n = 0; n < 4; ++n)
#pragma unroll
                    for (int r = 0; r < 4; ++r)
                        pm = fmaxf(pm, sacc[mt][n][r]);
                pm = fmaxf(pm, __shfl_xor(pm, 16));
                pm = fmaxf(pm, __shfl_xor(pm, 32));
                float mn = fmaxf(m_[mt], pm);
                float corr = __builtin_exp2f(m_[mt] - mn);
                m_[mt] = mn;
                float rs = 0.f;
#pragma unroll
                for (int n = 0; n < 4; ++n)
#pragma unroll
                    for (int r = 0; r < 4; ++r) {
                        float p = __builtin_exp2f(sacc[mt][n][r] - mn);
                        sacc[mt][n][r] = p;
                        rs += p;
                    }
                rs += __shfl_xor(rs, 16);
                rs += __shfl_xor(rs, 32);
                l_[mt] = l_[mt] * corr + rs;
                // ---- rescale yacc rows (corr lives at lane l15=q) ----
                int ci = __float_as_int(corr);
#pragma unroll
                for (int r = 0; r < 4; ++r) {
                    float cq = __int_as_float(
                        __builtin_amdgcn_ds_bpermute(vidx + 4 * r, ci));
#pragma unroll
                    for (int n = 0; n < 4; ++n) yacc[mt][n][r] *= cq;
                }
                // ---- pack P pairs -> per-wave LDS (row q=l15) ----
#pragma unroll
                for (int n = 0; n < 4; ++n)
#pragma unroll
                    for (int j = 0; j < 2; ++j) {
                        unsigned u = cvtpk_bf16(sacc[mt][n][2 * j],
                                                sacc[mt][n][2 * j + 1]);
                        int col = (n * 16 + lg * 4 + 2 * j) ^ ((l15 & 7) << 3);
                        *(unsigned*)&Pl[wid][mt * 16 + l15][col] = u;
                    }
            }
            // ---- Y += P V  (16x16x32, A = P from LDS, B = Vt) ----
#pragma unroll
            for (int ks = 0; ks < 2; ++ks) {
                bf16x8 pa[2], vf[4];
#pragma unroll
                for (int mt = 0; mt < 2; ++mt)
                    pa[mt] = *(const bf16x8*)&Pl[wid][mt * 16 + l15]
                               [(ks * 32 + lg * 8) ^ ((l15 & 7) << 3)];
#pragma unroll
                for (int nd = 0; nd < 4; ++nd) {
                    int d = nd * 16 + l15;
                    int sig = (d & 7) ^ ((d >> 3) & 7);
                    vf[nd] = *(const bf16x8*)&Vt[d]
                               [(ks * 32 + lg * 8) ^ (sig << 3)];
                }
#pragma unroll
                for (int mt = 0; mt < 2; ++mt)
#pragma unroll
                    for (int nd = 0; nd < 4; ++nd)
                        yacc[mt][nd] = __builtin_amdgcn_mfma_f32_16x16x32_bf16(
                            pa[mt], vf[nd], yacc[mt][nd], 0, 0, 0);
            }
        }
    }

    // ---- epilogue: Y / l  (l lives at lane l15=q; rows need lg*4+r) ----
#pragma unroll
    for (int mt = 0; mt < 2; ++mt) {
        float inv = 1.f / l_[mt];
        int ii = __float_as_int(inv);
        float iv[4];
#pragma unroll
        for (int r = 0; r < 4; ++r)
            iv[r] = __int_as_float(
                __builtin_amdgcn_ds_bpermute(vidx + 4 * r, ii));
#pragma unroll
        for (int n = 0; n < 4; ++n)
#pragma unroll
            for (int r = 0; r < 4; ++r) {
                int row = qbase + mt * 16 + lg * 4 + r;
                int d = n * 16 + l15;
                Yb[((size_t)(b * S_ + row)) * E_ + h * 64 + d] =
                    f2b(yacc[mt][n][r] * iv[r]);
            }
    }
}

extern "C" void kernel_launch(void* const* d_in, const int* in_sizes, int n_in,
                              void* d_out, int out_size, void* d_ws, size_t ws_size,
                              hipStream_t stream) {
    const float* x  = (const float*)d_in[0];
    const float* Wq = (const float*)d_in[1];
    const float* bq = (const float*)d_in[2];
    const float* Wk = (const float*)d_in[3];
    const float* bk = (const float*)d_in[4];
    const float* Wv = (const float*)d_in[5];
    const float* bv = (const float*)d_in[6];
    const float* Wo = (const float*)d_in[7];
    const float* bo = (const float*)d_in[8];

    char* ws = (char*)d_ws;
    const size_t M = (size_t)B_ * S_;  // 8192
    unsigned short* xb  = (unsigned short*)ws;                    // 16 MB (reused as Y)
    unsigned short* Wtq = (unsigned short*)(ws + (16ull << 20));  // 2 MB each
    unsigned short* Wtk = (unsigned short*)(ws + (18ull << 20));
    unsigned short* Wtv = (unsigned short*)(ws + (20ull << 20));
    unsigned short* Wto = (unsigned short*)(ws + (22ull << 20));
    unsigned short* Qb  = (unsigned short*)(ws + (24ull << 20));  // 16 MB
    unsigned short* Kb  = (unsigned short*)(ws + (40ull << 20));  // 16 MB
    unsigned short* Vb  = (unsigned short*)(ws + (56ull << 20));  // 16 MB
    unsigned short* Yb  = xb;                                     // reuse

    int n8 = (int)(M * E_ / 8);
    cvt_f32_to_bf16<<<(n8 + 255) / 256, 256, 0, stream>>>(x, xb, n8);

    dim3 tb(32, 8), tg(32, 32);
    transpose_cvt<<<tg, tb, 0, stream>>>(Wq, Wtq);
    transpose_cvt<<<tg, tb, 0, stream>>>(Wk, Wtk);
    transpose_cvt<<<tg, tb, 0, stream>>>(Wv, Wtv);
    transpose_cvt<<<tg, tb, 0, stream>>>(Wo, Wto);

    dim3 gg(E_ / BN, M / BM);  // (8, 64)
    gemm_bt<<<gg, 256, 0, stream>>>(xb, Wtq, bq, nullptr, Qb, (int)M, E_, E_);
    gemm_bt<<<gg, 256, 0, stream>>>(xb, Wtk, bk, nullptr, Kb, (int)M, E_, E_);
    gemm_bt<<<gg, 256, 0, stream>>>(xb, Wtv, bv, nullptr, Vb, (int)M, E_, E_);

    dim3 ag(B_ * H_, S_ / 128);  // (64, 16)
    attn_mfma<<<ag, 256, 0, stream>>>(Qb, Kb, Vb, Yb);

    gemm_bt<<<gg, 256, 0, stream>>>(Yb, Wto, bo, (float*)d_out, nullptr, (int)M, E_, E_);
}

// Round 6
// 229.907 us; speedup vs baseline: 7.0381x; 1.1046x over previous
//
#include <hip/hip_runtime.h>
#include <hip/hip_bf16.h>

#define B_ 4
#define S_ 2048
#define E_ 1024
#define H_ 16
#define HD_ 64
#define QS 3072   // fused QKV row stride

typedef __attribute__((ext_vector_type(8))) short bf16x8;
typedef __attribute__((ext_vector_type(4))) float f32x4;

__device__ __forceinline__ float b2f(unsigned short u) {
    union { unsigned u; float f; } v; v.u = ((unsigned)u) << 16; return v.f;
}
__device__ __forceinline__ unsigned short f2b(float f) {
    union { float f; unsigned u; } v; v.f = f;
    unsigned lsb = (v.u >> 16) & 1u;
    v.u += 0x7fffu + lsb;
    return (unsigned short)(v.u >> 16);
}
__device__ __forceinline__ unsigned cvtpk_bf16(float lo, float hi) {
    unsigned r;
    asm("v_cvt_pk_bf16_f32 %0, %1, %2" : "=v"(r) : "v"(lo), "v"(hi));
    return r;
}

// direct global -> LDS async copy, 16B per lane (linear dest = base + lane*16)
typedef const __attribute__((address_space(1))) unsigned glb_u32;
typedef __attribute__((address_space(3))) unsigned lds_u32;
__device__ __forceinline__ void gl_lds16(const unsigned short* g,
                                         unsigned short* l) {
    __builtin_amdgcn_global_load_lds((glb_u32*)g, (lds_u32*)l, 16, 0, 0);
}

// ---------------- elementwise f32 -> bf16 ----------------
__global__ void cvt_f32_to_bf16(const float* __restrict__ in,
                                unsigned short* __restrict__ out, int n8) {
    int i = blockIdx.x * blockDim.x + threadIdx.x;
    if (i >= n8) return;
    const float4* p = (const float4*)(in + (size_t)i * 8);
    float4 a = p[0], b = p[1];
    bf16x8 o;
    o[0] = (short)f2b(a.x); o[1] = (short)f2b(a.y);
    o[2] = (short)f2b(a.z); o[3] = (short)f2b(a.w);
    o[4] = (short)f2b(b.x); o[5] = (short)f2b(b.y);
    o[6] = (short)f2b(b.z); o[7] = (short)f2b(b.w);
    *(bf16x8*)(out + (size_t)i * 8) = o;
}

// ---------------- W[K][N] f32 -> Wt[N][K] bf16 ----------------
__global__ void transpose_cvt(const float* __restrict__ W,
                              unsigned short* __restrict__ Wt) {
    __shared__ float tile[32][33];
    int tx = threadIdx.x, ty = threadIdx.y;  // (32, 8)
    int x0 = blockIdx.x * 32, y0 = blockIdx.y * 32;
#pragma unroll
    for (int j = 0; j < 32; j += 8)
        tile[ty + j][tx] = W[(size_t)(y0 + ty + j) * E_ + x0 + tx];
    __syncthreads();
#pragma unroll
    for (int j = 0; j < 32; j += 8)
        Wt[(size_t)(x0 + ty + j) * E_ + y0 + tx] = f2b(tile[tx][ty + j]);
}

// ---------------- GEMM: C[M,N] = A[M,K] @ Bt[N,K]^T + bias ----------------
// bias selected among b0/b1/b2 by col>>10 (fused-QKV support)
#define BM 128
#define BN 128
#define BK 32

__global__ __launch_bounds__(256) void gemm_bt(
        const unsigned short* __restrict__ A,
        const unsigned short* __restrict__ Bt,
        const float* __restrict__ b0, const float* __restrict__ b1,
        const float* __restrict__ b2,
        float* __restrict__ Cf, unsigned short* __restrict__ Cb,
        int M, int N, int K) {
    __shared__ unsigned short As[BM][BK];
    __shared__ unsigned short Bs[BN][BK];
    int t = threadIdx.x;
    int lane = t & 63, wid = t >> 6;
    int wr = wid >> 1, wc = wid & 1;
    int bx = blockIdx.x, by = blockIdx.y;
    const int row = t >> 2, kc = (t & 3) << 3;
    const unsigned short* ga0 = A + (size_t)(by * BM + row) * K + kc;
    const unsigned short* gb0 = Bt + (size_t)(bx * BN + row) * K + kc;
    unsigned short* la0 = &As[0][0] + (size_t)t * 8;
    unsigned short* lb0 = &Bs[0][0] + (size_t)t * 8;
    const size_t step64 = (size_t)64 * K;

    f32x4 acc[4][4] = {};

    for (int ko = 0; ko < K; ko += BK) {
        gl_lds16(ga0 + ko, la0);
        gl_lds16(ga0 + ko + step64, la0 + 2048);
        gl_lds16(gb0 + ko, lb0);
        gl_lds16(gb0 + ko + step64, lb0 + 2048);
        __syncthreads();   // drains vmcnt(0) -> tiles resident
        int kg = (lane >> 4) << 3;  // k offset 0,8,16,24
        bf16x8 af[4], bfr[4];
#pragma unroll
        for (int i = 0; i < 4; ++i) {
            af[i]  = *(const bf16x8*)&As[wr * 64 + i * 16 + (lane & 15)][kg];
            bfr[i] = *(const bf16x8*)&Bs[wc * 64 + i * 16 + (lane & 15)][kg];
        }
#pragma unroll
        for (int i = 0; i < 4; ++i)
#pragma unroll
            for (int j = 0; j < 4; ++j)
                acc[i][j] = __builtin_amdgcn_mfma_f32_16x16x32_bf16(
                    af[i], bfr[j], acc[i][j], 0, 0, 0);
        __syncthreads();
    }

#pragma unroll
    for (int i = 0; i < 4; ++i) {
        int row0 = by * BM + wr * 64 + i * 16 + ((lane >> 4) << 2);
#pragma unroll
        for (int j = 0; j < 4; ++j) {
            int col = bx * BN + wc * 64 + j * 16 + (lane & 15);
            const float* bp = (col < 1024) ? b0 : ((col < 2048) ? b1 : b2);
            float bv = bp[col & 1023];
#pragma unroll
            for (int r = 0; r < 4; ++r) {
                int rr = row0 + r;
                float v = acc[i][j][r] + bv;
                if (Cf) Cf[(size_t)rr * N + col] = v;
                else    Cb[(size_t)rr * N + col] = f2b(v);
            }
        }
    }
}

// ---------------- causal flash attention, swapped-QK^T MFMA ----------------
// block = 4 waves; wave owns 32 q rows; KV tile = 64.
// Reads fused QKV buffer: row stride QS=3072, Q at +0, K at +1024, V at +2048.
#define KVBLK 64

__global__ __launch_bounds__(256) void attn_mfma(
        const unsigned short* __restrict__ QKV,
        unsigned short* __restrict__ Yb) {
    __shared__ unsigned short Ks[KVBLK][64];  // [key][d], col ^= (key&7)<<3
    __shared__ unsigned short Vt[64][KVBLK];  // [d][key], col ^= sig(d)<<3
    __shared__ unsigned short Pl[4][32][64];  // per-wave P[q][key], col ^= (q&7)<<3

    int t = threadIdx.x;
    int lane = t & 63, wid = t >> 6;
    int l15 = lane & 15, lg = lane >> 4;
    int bh = blockIdx.x;
    int b = bh >> 4, h = bh & 15;
    int by = gridDim.y - 1 - blockIdx.y;   // heavy blocks first
    int qbase = by * 128 + wid * 32;
    int vidx = lg << 4;                    // bpermute byte base: lane lg*4+r

    // ---- Q fragments, scale = 1/sqrt(64) * log2(e) (exp2 domain) ----
    const float qscale = 0.125f * 1.44269504f;
    bf16x8 qf[2][2];
#pragma unroll
    for (int mt = 0; mt < 2; ++mt)
#pragma unroll
        for (int ks = 0; ks < 2; ++ks) {
            int row = qbase + mt * 16 + l15;
            bf16x8 v = *(const bf16x8*)&QKV[((size_t)(b * S_ + row)) * QS +
                                            h * 64 + ks * 32 + lg * 8];
#pragma unroll
            for (int e = 0; e < 8; ++e)
                qf[mt][ks][e] = (short)f2b(b2f((unsigned short)v[e]) * qscale);
        }

    f32x4 yacc[2][4] = {};
    float m_[2] = {-1e30f, -1e30f}, l_[2] = {0.f, 0.f};

    int ntiles = by * 2 + 2;
    for (int kt = 0; kt < ntiles; ++kt) {
        int k0 = kt * KVBLK;
        __syncthreads();
        // ---- stage K (row-major) and V (transposed) ----
        {
            int key = t >> 2;            // 0..63
            int c4 = (t & 3) * 16;       // d base, 2 chunks of 8
            size_t g = ((size_t)(b * S_ + k0 + key)) * QS + 1024 + h * 64 + c4;
            bf16x8 k0v = *(const bf16x8*)&QKV[g];
            bf16x8 k1v = *(const bf16x8*)&QKV[g + 8];
            bf16x8 v0v = *(const bf16x8*)&QKV[g + 1024];
            bf16x8 v1v = *(const bf16x8*)&QKV[g + 1032];
            int swk = (key & 7) << 3;
            *(bf16x8*)&Ks[key][c4 ^ swk] = k0v;
            *(bf16x8*)&Ks[key][(c4 + 8) ^ swk] = k1v;
#pragma unroll
            for (int e = 0; e < 8; ++e) {
                int d0 = c4 + e, d1 = c4 + 8 + e;
                int s0 = (d0 & 7) ^ ((d0 >> 3) & 7);
                int s1 = (d1 & 7) ^ ((d1 >> 3) & 7);
                Vt[d0][key ^ (s0 << 3)] = (unsigned short)v0v[e];
                Vt[d1][key ^ (s1 << 3)] = (unsigned short)v1v[e];
            }
        }
        __syncthreads();

        if (k0 <= qbase + 31) {          // wave not fully masked
            bool boundary = (k0 + KVBLK - 1 > qbase);
            // ---- S^T = K Q^T : rows key (A side), cols q (B side) ----
            f32x4 sacc[2][4] = {};
#pragma unroll
            for (int ks = 0; ks < 2; ++ks) {
                bf16x8 kf[4];
#pragma unroll
                for (int n = 0; n < 4; ++n)
                    kf[n] = *(const bf16x8*)&Ks[n * 16 + l15]
                              [(ks * 32 + lg * 8) ^ ((l15 & 7) << 3)];
#pragma unroll
                for (int mt = 0; mt < 2; ++mt)
#pragma unroll
                    for (int n = 0; n < 4; ++n)
                        sacc[mt][n] = __builtin_amdgcn_mfma_f32_16x16x32_bf16(
                            kf[n], qf[mt][ks], sacc[mt][n], 0, 0, 0);
            }

#pragma unroll
            for (int mt = 0; mt < 2; ++mt) {
                int qv = qbase + mt * 16 + l15;   // this lane's q row
                if (boundary) {
#pragma unroll
                    for (int n = 0; n < 4; ++n)
#pragma unroll
                        for (int r = 0; r < 4; ++r)
                            if (k0 + n * 16 + lg * 4 + r > qv)
                                sacc[mt][n][r] = -3e38f;
                }
                // ---- online softmax over keys (in-reg + 2 shfl) ----
                float pm = -3e38f;
#pragma unroll
                for (int n = 0; n < 4; ++n)
#pragma unroll
                    for (int r = 0; r < 4; ++r)
                        pm = fmaxf(pm, sacc[mt][n][r]);
                pm = fmaxf(pm, __shfl_xor(pm, 16));
                pm = fmaxf(pm, __shfl_xor(pm, 32));
                float mn = fmaxf(m_[mt], pm);
                float corr = __builtin_exp2f(m_[mt] - mn);
                m_[mt] = mn;
                float rs = 0.f;
#pragma unroll
                for (int n = 0; n < 4; ++n)
#pragma unroll
                    for (int r = 0; r < 4; ++r) {
                        float p = __builtin_exp2f(sacc[mt][n][r] - mn);
                        sacc[mt][n][r] = p;
                        rs += p;
                    }
                rs += __shfl_xor(rs, 16);
                rs += __shfl_xor(rs, 32);
                l_[mt] = l_[mt] * corr + rs;
                // ---- rescale yacc rows (corr lives at lane l15=q) ----
                int ci = __float_as_int(corr);
#pragma unroll
                for (int r = 0; r < 4; ++r) {
                    float cq = __int_as_float(
                        __builtin_amdgcn_ds_bpermute(vidx + 4 * r, ci));
#pragma unroll
                    for (int n = 0; n < 4; ++n) yacc[mt][n][r] *= cq;
                }
                // ---- pack P pairs -> per-wave LDS (row q=l15) ----
#pragma unroll
                for (int n = 0; n < 4; ++n)
#pragma unroll
                    for (int j = 0; j < 2; ++j) {
                        unsigned u = cvtpk_bf16(sacc[mt][n][2 * j],
                                                sacc[mt][n][2 * j + 1]);
                        int col = (n * 16 + lg * 4 + 2 * j) ^ ((l15 & 7) << 3);
                        *(unsigned*)&Pl[wid][mt * 16 + l15][col] = u;
                    }
            }
            // ---- Y += P V  (16x16x32, A = P from LDS, B = Vt) ----
#pragma unroll
            for (int ks = 0; ks < 2; ++ks) {
                bf16x8 pa[2], vf[4];
#pragma unroll
                for (int mt = 0; mt < 2; ++mt)
                    pa[mt] = *(const bf16x8*)&Pl[wid][mt * 16 + l15]
                               [(ks * 32 + lg * 8) ^ ((l15 & 7) << 3)];
#pragma unroll
                for (int nd = 0; nd < 4; ++nd) {
                    int d = nd * 16 + l15;
                    int sig = (d & 7) ^ ((d >> 3) & 7);
                    vf[nd] = *(const bf16x8*)&Vt[d]
                               [(ks * 32 + lg * 8) ^ (sig << 3)];
                }
#pragma unroll
                for (int mt = 0; mt < 2; ++mt)
#pragma unroll
                    for (int nd = 0; nd < 4; ++nd)
                        yacc[mt][nd] = __builtin_amdgcn_mfma_f32_16x16x32_bf16(
                            pa[mt], vf[nd], yacc[mt][nd], 0, 0, 0);
            }
        }
    }

    // ---- epilogue: Y / l  (l lives at lane l15=q; rows need lg*4+r) ----
#pragma unroll
    for (int mt = 0; mt < 2; ++mt) {
        float inv = 1.f / l_[mt];
        int ii = __float_as_int(inv);
        float iv[4];
#pragma unroll
        for (int r = 0; r < 4; ++r)
            iv[r] = __int_as_float(
                __builtin_amdgcn_ds_bpermute(vidx + 4 * r, ii));
#pragma unroll
        for (int n = 0; n < 4; ++n)
#pragma unroll
            for (int r = 0; r < 4; ++r) {
                int row = qbase + mt * 16 + lg * 4 + r;
                int d = n * 16 + l15;
                Yb[((size_t)(b * S_ + row)) * E_ + h * 64 + d] =
                    f2b(yacc[mt][n][r] * iv[r]);
            }
    }
}

extern "C" void kernel_launch(void* const* d_in, const int* in_sizes, int n_in,
                              void* d_out, int out_size, void* d_ws, size_t ws_size,
                              hipStream_t stream) {
    const float* x  = (const float*)d_in[0];
    const float* Wq = (const float*)d_in[1];
    const float* bq = (const float*)d_in[2];
    const float* Wk = (const float*)d_in[3];
    const float* bk = (const float*)d_in[4];
    const float* Wv = (const float*)d_in[5];
    const float* bv = (const float*)d_in[6];
    const float* Wo = (const float*)d_in[7];
    const float* bo = (const float*)d_in[8];

    char* ws = (char*)d_ws;
    const size_t M = (size_t)B_ * S_;  // 8192
    unsigned short* xb   = (unsigned short*)ws;                    // 16 MB (reused as Y)
    unsigned short* QKVb = (unsigned short*)(ws + (16ull << 20));  // 48 MB
    unsigned short* Wqkv = (unsigned short*)(ws + (64ull << 20));  // 6 MB
    unsigned short* Wto  = (unsigned short*)(ws + (70ull << 20));  // 2 MB
    unsigned short* Yb   = xb;                                     // reuse

    int n8 = (int)(M * E_ / 8);
    cvt_f32_to_bf16<<<(n8 + 255) / 256, 256, 0, stream>>>(x, xb, n8);

    dim3 tb(32, 8), tg(32, 32);
    transpose_cvt<<<tg, tb, 0, stream>>>(Wq, Wqkv);
    transpose_cvt<<<tg, tb, 0, stream>>>(Wk, Wqkv + (size_t)1024 * E_);
    transpose_cvt<<<tg, tb, 0, stream>>>(Wv, Wqkv + (size_t)2048 * E_);
    transpose_cvt<<<tg, tb, 0, stream>>>(Wo, Wto);

    // fused QKV projection: C[8192][3072]
    dim3 gq(QS / BN, M / BM);  // (24, 64)
    gemm_bt<<<gq, 256, 0, stream>>>(xb, Wqkv, bq, bk, bv, nullptr, QKVb,
                                    (int)M, QS, E_);

    dim3 ag(B_ * H_, S_ / 128);  // (64, 16)
    attn_mfma<<<ag, 256, 0, stream>>>(QKVb, Yb);

    dim3 gg(E_ / BN, M / BM);  // (8, 64)
    gemm_bt<<<gg, 256, 0, stream>>>(Yb, Wto, bo, bo, bo, (float*)d_out, nullptr,
                                    (int)M, E_, E_);
}